// Round 12
// baseline (205.786 us; speedup 1.0000x reference)
//
#include <hip/hip_runtime.h>

// Decoder: h = relu(x @ W1 + b1); out = clamp(0.25*(h @ W2 + b2) + 0.5, 0, 1)
// B=262144, F=16, H=24, NOUT=784. Memory-bound: 822 MB fp32 output write.
//
// History:
//  R2:  fp32 fma, (256,2) -> 208 us.
//  R6:  f16 v_dot2, W2 strip in regs, (256,3) -> 182.5 us. BEST.
//  R8:  +pipeline+NT -> 201.8 (regr). R9: (256,4) neutral. R10: NT alone
//       -> 195 (harmful). R11: W2-in-LDS -> 185 neutral.
//  Model: phase-2 VALU *issue* (~53 us of 48 dot2 + clamp + store per row
//       per wave) serializes against the store stream; memory floor ~130 us.
//  This round: move the dot-products to the MFMA pipe.
//       Phase 2 = [256x24]@[24x784] -> mfma_f32_16x16x32_f16, K padded to 32
//       with zeros BOTH sides. h -> hbuf[256][32f16]; W2 -> LDS transposed
//       w2b[col][32f16] (pre-scaled 0.25, f16); bias folded into C-operand.
//       Per col-tile per wave: 1 ds_b128 + 1 ds_b32 + 2 MFMA + 8 clamp +
//       8 dword stores for 512 outputs (vs ~62 instr / 256 outputs before).

typedef _Float16 f16x8 __attribute__((ext_vector_type(8)));
typedef float    f32x4 __attribute__((ext_vector_type(4)));
typedef unsigned int u32;

static __device__ __forceinline__ u32 pk_h2(float lo, float hi) {
    return __builtin_bit_cast(u32, __builtin_amdgcn_cvt_pkrtz(lo, hi));
}

#define THREADS 512
#define ROWS 256
#define F 16
#define H 24
#define NOUT 784
#define NCOLT 49            // 784 / 16 column tiles
#define KP 12               // half2 pairs of real K (24)

__launch_bounds__(THREADS, 4)
__global__ void decoder_kernel(const float* __restrict__ x,
                               const float* __restrict__ W1,
                               const float* __restrict__ b1,
                               const float* __restrict__ W2,
                               const float* __restrict__ b2,
                               float* __restrict__ out) {
    __shared__ float w1t[H][F];          // 1.5 KB
    __shared__ float b1s[H];
    __shared__ u32   hbuf[ROWS][16];     // h as f16[32], K 24..31 = 0. 16 KB
    __shared__ u32   w2b[NOUT][16];      // W2' as f16[32] per col (transposed). 50 KB
    __shared__ float b2s[NOUT];          // folded bias. 3.1 KB

    const int tid  = threadIdx.x;
    const int row0 = blockIdx.x * ROWS;

    // ---- stage W1^T, b1
    for (int idx = tid; idx < F * H; idx += THREADS) {
        const int i = idx / H, j = idx % H;      // W1 is [F][H] row-major
        w1t[j][i] = W1[idx];
    }
    if (tid < H) b1s[tid] = b1[tid];

    // ---- stage folded bias: b2' = 0.25*b2 + 0.5
    for (int c = tid; c < NOUT; c += THREADS)
        b2s[c] = fmaf(b2[c], 0.25f, 0.5f);

    // ---- stage W2 transposed, f16-packed, pre-scaled 0.25.
    // item = col*12 + kp so consecutive tids walk kp fast (spread LDS banks).
    for (int item = tid; item < NOUT * KP; item += THREADS) {
        const int col = item / KP, kp = item - col * KP;
        const float a = W2[(2 * kp + 0) * NOUT + col];
        const float c = W2[(2 * kp + 1) * NOUT + col];
        w2b[col][kp] = pk_h2(0.25f * a, 0.25f * c);
    }
    for (int item = tid; item < NOUT * 4; item += THREADS) {   // zero K 24..31
        const int col = item >> 2, kp = 12 + (item & 3);
        w2b[col][kp] = 0u;
    }

    // ---- phase 1 (threads 0..255): h = relu(x @ W1 + b1), pack f16
    if (tid < ROWS) {
        float4 xv[4];
        const float* xr = x + (size_t)(row0 + tid) * F;
        #pragma unroll
        for (int q = 0; q < 4; ++q)
            xv[q] = *reinterpret_cast<const float4*>(&xr[q * 4]);

        #pragma unroll
        for (int g = 0; g < 3; ++g) {
            float hj[8];
            #pragma unroll
            for (int jj = 0; jj < 8; ++jj) {
                const int j = g * 8 + jj;
                float acc = b1s[j];
                #pragma unroll
                for (int q = 0; q < 4; ++q) {
                    const float4 wv = *reinterpret_cast<const float4*>(&w1t[j][q * 4]);
                    acc = fmaf(xv[q].x, wv.x, acc);
                    acc = fmaf(xv[q].y, wv.y, acc);
                    acc = fmaf(xv[q].z, wv.z, acc);
                    acc = fmaf(xv[q].w, wv.w, acc);
                }
                hj[jj] = fmaxf(acc, 0.0f);
            }
            uint4 p;
            p.x = pk_h2(hj[0], hj[1]);
            p.y = pk_h2(hj[2], hj[3]);
            p.z = pk_h2(hj[4], hj[5]);
            p.w = pk_h2(hj[6], hj[7]);
            *reinterpret_cast<uint4*>(&hbuf[tid][g * 4]) = p;
        }
        *reinterpret_cast<uint4*>(&hbuf[tid][12]) = make_uint4(0u, 0u, 0u, 0u);
    }

    __syncthreads();

    // ---- phase 2: MFMA. wave w owns row-tiles {2w, 2w+1} (rows 32w..32w+31).
    // Layouts (gfx950 16x16x32): A: m=lane&15, k=8*(lane>>4)+e.
    //                            B: n=lane&15, k=8*(lane>>4)+e.
    //                            D: m=4*(lane>>4)+r, n=lane&15.
    const int wave = tid >> 6;
    const int lane = tid & 63;
    const int lg   = lane >> 4;      // k-group (0..3)
    const int lm   = lane & 15;      // m or n within tile

    const f16x8 a0 = __builtin_bit_cast(f16x8,
        *reinterpret_cast<const uint4*>(&hbuf[wave * 32 + lm][lg * 4]));
    const f16x8 a1 = __builtin_bit_cast(f16x8,
        *reinterpret_cast<const uint4*>(&hbuf[wave * 32 + 16 + lm][lg * 4]));

    // lane's output base: row (wave*32 + lg*4), col lm
    float* outp = out + ((size_t)row0 + wave * 32 + lg * 4) * NOUT + lm;

    for (int ct = 0; ct < NCOLT; ++ct) {
        const int cb = ct * 16;
        const f16x8 bf = __builtin_bit_cast(f16x8,
            *reinterpret_cast<const uint4*>(&w2b[cb + lm][lg * 4]));
        const float bb = b2s[cb + lm];
        f32x4 acc0 = {bb, bb, bb, bb};
        f32x4 acc1 = {bb, bb, bb, bb};
        acc0 = __builtin_amdgcn_mfma_f32_16x16x32_f16(a0, bf, acc0, 0, 0, 0);
        acc1 = __builtin_amdgcn_mfma_f32_16x16x32_f16(a1, bf, acc1, 0, 0, 0);

        float* p = outp + cb;
        #pragma unroll
        for (int r = 0; r < 4; ++r) {
            p[(size_t)r * NOUT]        = fminf(fmaxf(acc0[r], 0.f), 1.f);
            p[(size_t)(16 + r) * NOUT] = fminf(fmaxf(acc1[r], 0.f), 1.f);
        }
    }
}

extern "C" void kernel_launch(void* const* d_in, const int* in_sizes, int n_in,
                              void* d_out, int out_size, void* d_ws, size_t ws_size,
                              hipStream_t stream) {
    const float* x  = (const float*)d_in[0];
    const float* W1 = (const float*)d_in[1];
    const float* b1 = (const float*)d_in[2];
    const float* W2 = (const float*)d_in[3];
    const float* b2 = (const float*)d_in[4];
    float* out = (float*)d_out;

    const int B = in_sizes[0] / F;              // 262144
    const int grid = B / ROWS;                  // 1024
    decoder_kernel<<<grid, THREADS, 0, stream>>>(x, W1, b1, W2, b2, out);
}

// Round 13
// 201.499 us; speedup vs baseline: 1.0213x; 1.0213x over previous
//
#include <hip/hip_runtime.h>

// Decoder: h = relu(x @ W1 + b1); out = clamp(0.25*(h @ W2 + b2) + 0.5, 0, 1)
// B=262144, F=16, H=24, NOUT=784. Memory-bound: 822 MB fp32 output write.
//
// History:
//  R6:  f16 v_dot2 VALU kernel -> 182.5 us. Prior best.
//  R12: MFMA (h as A, W2 as B): correct but 205.8 us. Epilogue flaws:
//       dword-granular scattered stores (4x store issue) + 8-way bank
//       conflict on w2b reads in the hot loop.
//  This round: SWAP MFMA operands -> D = W2^T-tile x h-tile. Lane then owns
//       4 CONTIGUOUS out-cols of one row -> float4 stores (R6's store shape).
//       + XOR-swizzle w2b quads (4-way instead of 8-way conflict)
//       + v_med3 clamp (finite inputs), bias in C-operand.
//       Per wave per col-tile: 2 ds_b128 + 2 MFMA + 8 med3 + 2 float4 stores.

typedef _Float16 f16x8 __attribute__((ext_vector_type(8)));
typedef float    f32x4 __attribute__((ext_vector_type(4)));
typedef unsigned int u32;

static __device__ __forceinline__ u32 pk_h2(float lo, float hi) {
    return __builtin_bit_cast(u32, __builtin_amdgcn_cvt_pkrtz(lo, hi));
}

#define THREADS 512
#define ROWS 256
#define F 16
#define H 24
#define NOUT 784
#define NCOLT 49            // 784 / 16 column tiles
#define KP 12               // half2 pairs of real K (24)

__launch_bounds__(THREADS, 4)
__global__ void decoder_kernel(const float* __restrict__ x,
                               const float* __restrict__ W1,
                               const float* __restrict__ b1,
                               const float* __restrict__ W2,
                               const float* __restrict__ b2,
                               float* __restrict__ out) {
    __shared__ float w1t[H][F];          // 1.5 KB
    __shared__ float b1s[H];
    __shared__ u32   hbuf[ROWS][16];     // h as f16[32], K 24..31 = 0. 16 KB
    __shared__ u32   w2b[NOUT][16];      // W2' f16[32]/col, quad-swizzled. 50 KB
    __shared__ float b2s[NOUT];          // folded bias. 3.1 KB
    // total ~71 KB -> 2 blocks/CU, 16 waves/CU

    const int tid  = threadIdx.x;
    const int row0 = blockIdx.x * ROWS;

    // ---- stage W1^T, b1
    for (int idx = tid; idx < F * H; idx += THREADS) {
        const int i = idx / H, j = idx % H;      // W1 is [F][H] row-major
        w1t[j][i] = W1[idx];
    }
    if (tid < H) b1s[tid] = b1[tid];

    // ---- stage folded bias: b2' = 0.25*b2 + 0.5
    for (int c = tid; c < NOUT; c += THREADS)
        b2s[c] = fmaf(b2[c], 0.25f, 0.5f);

    // ---- stage W2 transposed, f16-packed, pre-scaled 0.25.
    // Quad-swizzle the u32 index: idx = kp ^ ((col&3)<<2). XOR touches only
    // bits[3:2], so each b128 quad stays contiguous; reads spread over 4
    // bank-quads (4-way, ~free) instead of 2 banks (8-way).
    for (int item = tid; item < NOUT * KP; item += THREADS) {
        const int col = item / KP, kp = item - col * KP;
        const float a = W2[(2 * kp + 0) * NOUT + col];
        const float c = W2[(2 * kp + 1) * NOUT + col];
        w2b[col][kp ^ ((col & 3) << 2)] = pk_h2(0.25f * a, 0.25f * c);
    }
    for (int item = tid; item < NOUT * 4; item += THREADS) {   // zero K 24..31
        const int col = item >> 2, kp = 12 + (item & 3);
        w2b[col][kp ^ ((col & 3) << 2)] = 0u;
    }

    // ---- phase 1 (threads 0..255): h = relu(x @ W1 + b1), pack f16
    if (tid < ROWS) {
        float4 xv[4];
        const float* xr = x + (size_t)(row0 + tid) * F;
        #pragma unroll
        for (int q = 0; q < 4; ++q)
            xv[q] = *reinterpret_cast<const float4*>(&xr[q * 4]);

        #pragma unroll
        for (int g = 0; g < 3; ++g) {
            float hj[8];
            #pragma unroll
            for (int jj = 0; jj < 8; ++jj) {
                const int j = g * 8 + jj;
                float acc = b1s[j];
                #pragma unroll
                for (int q = 0; q < 4; ++q) {
                    const float4 wv = *reinterpret_cast<const float4*>(&w1t[j][q * 4]);
                    acc = fmaf(xv[q].x, wv.x, acc);
                    acc = fmaf(xv[q].y, wv.y, acc);
                    acc = fmaf(xv[q].z, wv.z, acc);
                    acc = fmaf(xv[q].w, wv.w, acc);
                }
                hj[jj] = fmaxf(acc, 0.0f);
            }
            uint4 p;
            p.x = pk_h2(hj[0], hj[1]);
            p.y = pk_h2(hj[2], hj[3]);
            p.z = pk_h2(hj[4], hj[5]);
            p.w = pk_h2(hj[6], hj[7]);
            *reinterpret_cast<uint4*>(&hbuf[tid][g * 4]) = p;
        }
        *reinterpret_cast<uint4*>(&hbuf[tid][12]) = make_uint4(0u, 0u, 0u, 0u);
    }

    __syncthreads();

    // ---- phase 2: MFMA with SWAPPED operands.
    // D = A.B, A[m][k] = W2'[k][cb+m] (m = out-col-local), B[k][n] =
    // h[rowtile+n][k] (n = row-local). Fragment layouts (verified R12):
    //   A: m = lane&15, k = 8*(lane>>4)+e   -> load w2b[cb+lm]
    //   B: n = lane&15, k = 8*(lane>>4)+e   -> load hbuf[rowtile+lm]
    //   C/D: m = 4*(lane>>4)+r, n = lane&15 -> lane owns out[row0+rt+lm]
    //                                          [cb + 4*lg + r], r=0..3
    const int wave = tid >> 6;
    const int lane = tid & 63;
    const int lg   = lane >> 4;
    const int lm   = lane & 15;

    const f16x8 hA = __builtin_bit_cast(f16x8,
        *reinterpret_cast<const uint4*>(&hbuf[wave * 32 + lm][lg * 4]));
    const f16x8 hB = __builtin_bit_cast(f16x8,
        *reinterpret_cast<const uint4*>(&hbuf[wave * 32 + 16 + lm][lg * 4]));

    float* out0 = out + ((size_t)row0 + wave * 32 + lm) * NOUT + lg * 4;
    float* out1 = out0 + (size_t)16 * NOUT;
    const int wsw = (lg * 4) ^ ((lm & 3) << 2);   // swizzled quad base

    for (int ct = 0; ct < NCOLT; ++ct) {
        const int cb = ct * 16;
        const f16x8 wf = __builtin_bit_cast(f16x8,
            *reinterpret_cast<const uint4*>(&w2b[cb + lm][wsw]));
        const float4 bb = *reinterpret_cast<const float4*>(&b2s[cb + lg * 4]);
        f32x4 acc0 = {bb.x, bb.y, bb.z, bb.w};
        f32x4 acc1 = acc0;
        acc0 = __builtin_amdgcn_mfma_f32_16x16x32_f16(wf, hA, acc0, 0, 0, 0);
        acc1 = __builtin_amdgcn_mfma_f32_16x16x32_f16(wf, hB, acc1, 0, 0, 0);

        float4 o0, o1;
        o0.x = __builtin_amdgcn_fmed3f(acc0[0], 0.f, 1.f);
        o0.y = __builtin_amdgcn_fmed3f(acc0[1], 0.f, 1.f);
        o0.z = __builtin_amdgcn_fmed3f(acc0[2], 0.f, 1.f);
        o0.w = __builtin_amdgcn_fmed3f(acc0[3], 0.f, 1.f);
        o1.x = __builtin_amdgcn_fmed3f(acc1[0], 0.f, 1.f);
        o1.y = __builtin_amdgcn_fmed3f(acc1[1], 0.f, 1.f);
        o1.z = __builtin_amdgcn_fmed3f(acc1[2], 0.f, 1.f);
        o1.w = __builtin_amdgcn_fmed3f(acc1[3], 0.f, 1.f);
        *reinterpret_cast<float4*>(out0 + cb) = o0;
        *reinterpret_cast<float4*>(out1 + cb) = o1;
    }
}

extern "C" void kernel_launch(void* const* d_in, const int* in_sizes, int n_in,
                              void* d_out, int out_size, void* d_ws, size_t ws_size,
                              hipStream_t stream) {
    const float* x  = (const float*)d_in[0];
    const float* W1 = (const float*)d_in[1];
    const float* b1 = (const float*)d_in[2];
    const float* W2 = (const float*)d_in[3];
    const float* b2 = (const float*)d_in[4];
    float* out = (float*)d_out;

    const int B = in_sizes[0] / F;              // 262144
    const int grid = B / ROWS;                  // 1024
    decoder_kernel<<<grid, THREADS, 0, stream>>>(x, W1, b1, W2, b2, out);
}

// Round 14
// 184.680 us; speedup vs baseline: 1.1143x; 1.0911x over previous
//
#include <hip/hip_runtime.h>

// Decoder: h = relu(x @ W1 + b1); out = clamp(0.25*(h @ W2 + b2) + 0.5, 0, 1)
// B=262144, F=16, H=24, NOUT=784. Memory-bound: 822 MB fp32 output write.
//
// History:
//  R6:  f16 v_dot2, 256 thr / 256 rows, grid 1024, (256,3) -> 182.5 us. BEST.
//  R8-R11: pipeline/NT/occupancy/W2-LDS all neutral-or-worse.
//  R12/R13: MFMA phase-2 (2 variants incl. float4-store epilogue) -> 202-206.
//       6x less issue, SLOWER => issue occupancy was never the limiter.
//  Everything clusters 183-206 us vs ~130 us pure-store floor. Remaining
//  structural suspect: 4 block-generations/CU, each paying a serial head
//  (x-load latency + phase1 + 2 barriers, no stores issuing) + inter-
//  generation store-ramp gap.
//  This round: ONE GENERATION. 1024 threads, 1024 rows/block, grid=256
//  (1 block/CU). Thread quarter q=tid>>8 runs R6's exact phase-2 loop over
//  rows q*256..q*256+255. Per-thread state identical to R6 (48-reg W2 strip,
//  proven no-spill at cap 128 in R9). Prologue once instead of 4x.

typedef _Float16 h2_t __attribute__((ext_vector_type(2)));

static __device__ __forceinline__ unsigned int pk_h2(float lo, float hi) {
    return __builtin_bit_cast(unsigned int, __builtin_amdgcn_cvt_pkrtz(lo, hi));
}

#if __has_builtin(__builtin_amdgcn_fdot2)
static __device__ __forceinline__ float fdot2u(unsigned int a, unsigned int b, float c) {
    return __builtin_amdgcn_fdot2(__builtin_bit_cast(h2_t, a),
                                  __builtin_bit_cast(h2_t, b), c, false);
}
#else
static __device__ __forceinline__ float fdot2u(unsigned int a, unsigned int b, float c) {
    const h2_t av = __builtin_bit_cast(h2_t, a);
    const h2_t bv = __builtin_bit_cast(h2_t, b);
    return fmaf((float)av.y, (float)bv.y, fmaf((float)av.x, (float)bv.x, c));
}
#endif

#define THREADS 1024
#define ROWS 1024           // rows per block (= per CU, single generation)
#define QROWS 256           // rows per thread-quarter
#define F 16
#define H 24
#define KP 12               // half2 pairs along K=24
#define NOUT 784
#define NCHUNK (NOUT / 4)   // 196 float4 column-chunks per row

__launch_bounds__(THREADS, 4)
__global__ void decoder_kernel(const float* __restrict__ x,
                               const float* __restrict__ W1,
                               const float* __restrict__ b1,
                               const float* __restrict__ W2,
                               const float* __restrict__ b2,
                               float* __restrict__ out) {
    __shared__ float w1t[H][F];                 // W1^T, 1.5 KB
    __shared__ float b1s[H];
    __shared__ unsigned int hbuf[ROWS][KP];     // h packed half2, 48 KB

    const int tid  = threadIdx.x;
    const int row0 = blockIdx.x * ROWS;

    // ---- stage W1^T and b1 into LDS
    for (int idx = tid; idx < F * H; idx += THREADS) {
        const int i = idx / H, j = idx % H;     // W1 is [F][H] row-major
        w1t[j][i] = W1[idx];
    }
    if (tid < H) b1s[tid] = b1[tid];

    // ---- load this thread's x row (16 floats = 4 x float4)
    float4 xv[4];
    {
        const float* xr = x + (size_t)(row0 + tid) * F;
        #pragma unroll
        for (int q = 0; q < 4; ++q)
            xv[q] = *reinterpret_cast<const float4*>(&xr[q * 4]);
    }

    __syncthreads();

    // ---- phase 1: h = relu(x @ W1 + b1) for row (row0 + tid); pack f16
    #pragma unroll
    for (int g = 0; g < 3; ++g) {
        float hj[8];
        #pragma unroll
        for (int jj = 0; jj < 8; ++jj) {
            const int j = g * 8 + jj;
            float acc = b1s[j];
            #pragma unroll
            for (int q = 0; q < 4; ++q) {
                const float4 wv = *reinterpret_cast<const float4*>(&w1t[j][q * 4]);
                acc = fmaf(xv[q].x, wv.x, acc);
                acc = fmaf(xv[q].y, wv.y, acc);
                acc = fmaf(xv[q].z, wv.z, acc);
                acc = fmaf(xv[q].w, wv.w, acc);
            }
            hj[jj] = fmaxf(acc, 0.0f);
        }
        uint4 p;
        p.x = pk_h2(hj[0], hj[1]);
        p.y = pk_h2(hj[2], hj[3]);
        p.z = pk_h2(hj[4], hj[5]);
        p.w = pk_h2(hj[6], hj[7]);
        *reinterpret_cast<uint4*>(&hbuf[tid][g * 4]) = p;
    }

    __syncthreads();

    // ---- phase 2: quarter q = tid>>8 handles rows q*256..q*256+255;
    // within the quarter, thread owns output cols [c0, c0+3] (R6's layout).
    const int qt  = tid >> 8;                   // 0..3
    const int lt  = tid & 255;                  // R6's tid
    const int cc  = (lt < NCHUNK) ? lt : (NCHUNK - 1);   // clamp, no branch
    const int c0  = cc * 4;
    const int rq0 = qt * QROWS;

    unsigned int w2p[KP][4];
    #pragma unroll
    for (int kp = 0; kp < KP; ++kp) {
        const float4 a = *reinterpret_cast<const float4*>(&W2[(2 * kp + 0) * NOUT + c0]);
        const float4 b = *reinterpret_cast<const float4*>(&W2[(2 * kp + 1) * NOUT + c0]);
        w2p[kp][0] = pk_h2(0.25f * a.x, 0.25f * b.x);
        w2p[kp][1] = pk_h2(0.25f * a.y, 0.25f * b.y);
        w2p[kp][2] = pk_h2(0.25f * a.z, 0.25f * b.z);
        w2p[kp][3] = pk_h2(0.25f * a.w, 0.25f * b.w);
    }
    float4 b2v = *reinterpret_cast<const float4*>(&b2[c0]);
    b2v.x = fmaf(b2v.x, 0.25f, 0.5f);
    b2v.y = fmaf(b2v.y, 0.25f, 0.5f);
    b2v.z = fmaf(b2v.z, 0.25f, 0.5f);
    b2v.w = fmaf(b2v.w, 0.25f, 0.5f);

    if (lt < NCHUNK) {
        float* outp = out + (size_t)(row0 + rq0) * NOUT + c0;
        for (int r = 0; r < QROWS; ++r) {
            // h row: 3 uniform-address (broadcast) b128 reads = 12 half2
            const uint4 h0 = *reinterpret_cast<const uint4*>(&hbuf[rq0 + r][0]);
            const uint4 h1 = *reinterpret_cast<const uint4*>(&hbuf[rq0 + r][4]);
            const uint4 h2 = *reinterpret_cast<const uint4*>(&hbuf[rq0 + r][8]);
            unsigned int hw[KP];
            hw[0] = h0.x; hw[1]  = h0.y; hw[2]  = h0.z; hw[3]  = h0.w;
            hw[4] = h1.x; hw[5]  = h1.y; hw[6]  = h1.z; hw[7]  = h1.w;
            hw[8] = h2.x; hw[9]  = h2.y; hw[10] = h2.z; hw[11] = h2.w;

            float4 acc = b2v;
            #pragma unroll
            for (int kp = 0; kp < KP; ++kp) {
                acc.x = fdot2u(hw[kp], w2p[kp][0], acc.x);
                acc.y = fdot2u(hw[kp], w2p[kp][1], acc.y);
                acc.z = fdot2u(hw[kp], w2p[kp][2], acc.z);
                acc.w = fdot2u(hw[kp], w2p[kp][3], acc.w);
            }
            float4 o;
            o.x = fminf(fmaxf(acc.x, 0.f), 1.f);
            o.y = fminf(fmaxf(acc.y, 0.f), 1.f);
            o.z = fminf(fmaxf(acc.z, 0.f), 1.f);
            o.w = fminf(fmaxf(acc.w, 0.f), 1.f);
            *reinterpret_cast<float4*>(outp) = o;
            outp += NOUT;
        }
    }
}

extern "C" void kernel_launch(void* const* d_in, const int* in_sizes, int n_in,
                              void* d_out, int out_size, void* d_ws, size_t ws_size,
                              hipStream_t stream) {
    const float* x  = (const float*)d_in[0];
    const float* W1 = (const float*)d_in[1];
    const float* b1 = (const float*)d_in[2];
    const float* W2 = (const float*)d_in[3];
    const float* b2 = (const float*)d_in[4];
    float* out = (float*)d_out;

    const int B = in_sizes[0] / F;              // 262144
    const int grid = B / ROWS;                  // 256 = 1 block per CU
    decoder_kernel<<<grid, THREADS, 0, stream>>>(x, W1, b1, W2, b2, out);
}